// Round 7
// baseline (25.169 us; speedup 1.0000x reference)
//
#include <hip/hip_runtime.h>
#include <math.h>

// FFA forward: h[t] = lambda*h[t-1] + x[t], lambda[m,c] = exp(a_m + i b_c)
// Output = REAL PART of h[t], float32, shape (B,T,MEM,CTX).
//
// Fused single kernel. Block = (b, m-pair): 512 threads = (s:64, m2:2, cq:4).
// Each thread owns FOUR adjacent c (c-quad -> ILP=4, one 16B float4 store
// per timestep, one x load feeds 4 states) and a segment of KCH=32 steps.
//   A) per-thread: segment-local end states (zero init) -> LDS
//   B) 32 lanes: serial affine scan over 64 segment states per (m2,c),
//      seeded from the memory input -> incoming state per segment
//   C) per-thread: replay segment, store float4 {Re c0..c3} (16 B/lane,
//      8 lanes = full 128 B line per (m-pair); matches the 6.5 TB/s
//      fill-kernel store width).
// XCD swizzle: 256 blocks = 8 XCDs x 32; XCD k owns batch b=k so x[b]
// (512 KB) stays L2-resident across both passes; per-block x slice is
// 16 KB -> L1-resident for the phase-C reload.

#define BB   8
#define TT   2048
#define MEMD 64
#define CTXD 16
#define KCH  32                 // per-thread segment length
#define NSEG (TT / KCH)         // 64 segments

__device__ __forceinline__ float2 cmul(float2 u, float2 v) {
    return make_float2(u.x * v.x - u.y * v.y, u.x * v.y + u.y * v.x);
}

__device__ __forceinline__ float clip_a(float a) {
    const float LIMIT = (float)(88.72283911167299 / 1024.0 - 0.01); // log(F32_MAX)/MAX_LEN - FUDGE
    return fminf(fmaxf(a, -LIMIT), -1e-8f);
}

__global__ __launch_bounds__(512) void ffa_fused(
        const float* __restrict__ x,
        const float* __restrict__ mem_r,
        const float* __restrict__ mem_i,
        const float* __restrict__ a,
        const float* __restrict__ bfreq,
        float* __restrict__ out) {
    // S[m2][c][s], row stride NSEG+1 (odd 130-dword lane stride in the scan
    // phase -> only 2-way bank aliasing, free).
    __shared__ float2 S[2][CTXD][NSEG + 1];

    // Bijective XCD-contiguous swizzle (256 = 8 * 32): XCD k gets logical
    // blocks k*32..k*32+31 = all 32 m-pairs of batch b=k.
    int bid = blockIdx.x;
    int L = (bid & 7) * 32 + (bid >> 3);
    int b = L >> 5;
    int m0 = (L & 31) * 2;

    int tid = threadIdx.x;
    int cq = tid & 3;            // c-quad index: c0 = 4*cq
    int m2 = (tid >> 2) & 1;
    int s  = tid >> 3;           // segment 0..63
    int m = m0 + m2;
    int c0 = cq * 4;

    float am = clip_a(a[m]);
    float ea = expf(am);
    float2 lam0, lam1, lam2, lam3;
    {
        float b0 = bfreq[c0], b1 = bfreq[c0+1], b2 = bfreq[c0+2], b3 = bfreq[c0+3];
        lam0 = make_float2(ea * cosf(b0), ea * sinf(b0));
        lam1 = make_float2(ea * cosf(b1), ea * sinf(b1));
        lam2 = make_float2(ea * cosf(b2), ea * sinf(b2));
        lam3 = make_float2(ea * cosf(b3), ea * sinf(b3));
    }

    const float* xp = x + ((size_t)(b * TT + s * KCH)) * MEMD + m;

    // Phase A: segment-local states, zero init. One x load feeds 4 states.
    float2 h0 = make_float2(0.f, 0.f), h1 = h0, h2 = h0, h3 = h0;
#pragma unroll 8
    for (int t = 0; t < KCH; ++t) {
        float xv = xp[(size_t)t * MEMD];
        h0 = cmul(lam0, h0); h0.x += xv;
        h1 = cmul(lam1, h1); h1.x += xv;
        h2 = cmul(lam2, h2); h2.x += xv;
        h3 = cmul(lam3, h3); h3.x += xv;
    }
    S[m2][c0    ][s] = h0;
    S[m2][c0 + 1][s] = h1;
    S[m2][c0 + 2][s] = h2;
    S[m2][c0 + 3][s] = h3;
    __syncthreads();

    // Phase B: serial affine scan over segments, 32 lanes (one per (m2,c)).
    // In-place: S[m2][c][s] becomes the INCOMING state for segment s.
    if (tid < 32) {
        int cc = tid & (CTXD - 1);
        int lm2 = tid >> 4;
        int sm = m0 + lm2;
        float sam = clip_a(a[sm]);
        float sbc = bfreq[cc];
        float eaK = expf(sam * (float)KCH);
        float argK = sbc * (float)KCH;
        float2 lamK = make_float2(eaK * cosf(argK), eaK * sinf(argK));
        int seq = (b * MEMD + sm) * CTXD + cc;
        float2 hh = make_float2(mem_r[seq], mem_i[seq]);
#pragma unroll 8
        for (int ss = 0; ss < NSEG; ++ss) {
            float2 sv = S[lm2][cc][ss];
            S[lm2][cc][ss] = hh;
            hh = cmul(lamK, hh);
            hh.x += sv.x;
            hh.y += sv.y;
        }
    }
    __syncthreads();

    // Phase C: replay segment from exact incoming state; store float4 of
    // the 4 real parts (16 B per lane, full 128 B lines per m-pair group).
    h0 = S[m2][c0    ][s];
    h1 = S[m2][c0 + 1][s];
    h2 = S[m2][c0 + 2][s];
    h3 = S[m2][c0 + 3][s];
    float* op = out + (((size_t)(b * TT + s * KCH)) * MEMD + m) * CTXD + c0;
#pragma unroll 4
    for (int t = 0; t < KCH; ++t) {
        float xv = xp[(size_t)t * MEMD];
        h0 = cmul(lam0, h0); h0.x += xv;
        h1 = cmul(lam1, h1); h1.x += xv;
        h2 = cmul(lam2, h2); h2.x += xv;
        h3 = cmul(lam3, h3); h3.x += xv;
        *reinterpret_cast<float4*>(op + (size_t)t * (MEMD * CTXD)) =
            make_float4(h0.x, h1.x, h2.x, h3.x);
    }
}

extern "C" void kernel_launch(void* const* d_in, const int* in_sizes, int n_in,
                              void* d_out, int out_size, void* d_ws, size_t ws_size,
                              hipStream_t stream) {
    const float* x     = (const float*)d_in[0];
    const float* mem_r = (const float*)d_in[1];
    const float* mem_i = (const float*)d_in[2];
    const float* a     = (const float*)d_in[3];
    const float* bfrq  = (const float*)d_in[4];
    float* out = (float*)d_out;

    ffa_fused<<<BB * (MEMD / 2), 512, 0, stream>>>(x, mem_r, mem_i, a, bfrq, out);
}

// Round 8
// 22.006 us; speedup vs baseline: 1.1437x; 1.1437x over previous
//
#include <hip/hip_runtime.h>
#include <math.h>

// FFA forward: h[t] = lambda*h[t-1] + x[t], lambda[m,c] = exp(a_m + i b_c)
// Output = REAL PART of h[t], float32, shape (B,T,MEM,CTX).
//
// R5 structure (best measured: 22.1 us) + non-temporal output stores.
// Block = (b, m-pair): 1024 threads = (j:32, m2:2, c:16).
//   A) each thread: chunk-local end state (zero init) -> LDS
//   B) 32 lanes: serial affine scan over 32 chunk states seeded from memory
//   C) each thread: replay chunk, nontemporal-store real part (4 B/lane,
//      32 consecutive lanes = aligned 128 B line; nt keeps the 67 MB
//      write stream out of the per-XCD L2 so x stays resident).
// XCD swizzle: 256 blocks = 8 XCDs x 32; XCD k owns batch b=k.

#define BB   8
#define TT   2048
#define MEMD 64
#define CTXD 16
#define KC   64                 // chunk length in time
#define NCH  (TT / KC)          // 32 chunks

__device__ __forceinline__ float2 cmul(float2 u, float2 v) {
    return make_float2(u.x * v.x - u.y * v.y, u.x * v.y + u.y * v.x);
}

__device__ __forceinline__ float clip_a(float a) {
    const float LIMIT = (float)(88.72283911167299 / 1024.0 - 0.01); // log(F32_MAX)/MAX_LEN - FUDGE
    return fminf(fmaxf(a, -LIMIT), -1e-8f);
}

__global__ __launch_bounds__(1024) void ffa_fused(
        const float* __restrict__ x,
        const float* __restrict__ mem_r,
        const float* __restrict__ mem_i,
        const float* __restrict__ a,
        const float* __restrict__ bfreq,
        float* __restrict__ out) {
    // S[m2][c][j], row stride 33 float2 -> 2-way bank aliasing only (free).
    __shared__ float2 S[2][CTXD][NCH + 1];

    // Bijective XCD-contiguous swizzle (256 = 8 * 32): XCD k gets logical
    // blocks k*32..k*32+31 = all 32 m-pairs of batch b=k.
    int bid = blockIdx.x;
    int L = (bid & 7) * 32 + (bid >> 3);
    int b = L >> 5;
    int m0 = (L & 31) * 2;

    int tid = threadIdx.x;
    int c = tid & (CTXD - 1);
    int m2 = (tid >> 4) & 1;
    int j = tid >> 5;
    int m = m0 + m2;

    float am = clip_a(a[m]);
    float bc = bfreq[c];
    float ea = expf(am);
    float2 lam = make_float2(ea * cosf(bc), ea * sinf(bc));

    const float* xp = x + ((size_t)(b * TT + j * KC)) * MEMD + m;

    // Phase A: chunk-local state, zero init. 16 c-lanes broadcast each x load.
    float2 h = make_float2(0.f, 0.f);
#pragma unroll 8
    for (int t = 0; t < KC; ++t) {
        float xv = xp[(size_t)t * MEMD];
        h = cmul(lam, h);
        h.x += xv;
    }
    S[m2][c][j] = h;
    __syncthreads();

    // Phase B: serial affine scan over chunks, 32 lanes (one per (m2,c)).
    // In-place: S[m2][c][j] becomes the INCOMING state for chunk j.
    if (tid < 32) {
        float eaK = expf(am * (float)KC);
        float argK = bc * (float)KC;
        float2 lamK = make_float2(eaK * cosf(argK), eaK * sinf(argK));
        int seq = (b * MEMD + m) * CTXD + c;
        float2 hh = make_float2(mem_r[seq], mem_i[seq]);
#pragma unroll 8
        for (int jj = 0; jj < NCH; ++jj) {
            float2 s = S[m2][c][jj];
            S[m2][c][jj] = hh;
            hh = cmul(lamK, hh);
            hh.x += s.x;
            hh.y += s.y;
        }
    }
    __syncthreads();

    // Phase C: replay chunk from exact incoming state; nontemporal-store
    // the real part. 32 lanes x 4 B = 128 B aligned contiguous per group.
    h = S[m2][c][j];
    float* op = out + ((size_t)(b * TT + j * KC) * MEMD + m) * CTXD + c;
#pragma unroll 8
    for (int t = 0; t < KC; ++t) {
        float xv = xp[(size_t)t * MEMD];
        h = cmul(lam, h);
        h.x += xv;
        __builtin_nontemporal_store(h.x, op + (size_t)t * (MEMD * CTXD));
    }
}

extern "C" void kernel_launch(void* const* d_in, const int* in_sizes, int n_in,
                              void* d_out, int out_size, void* d_ws, size_t ws_size,
                              hipStream_t stream) {
    const float* x     = (const float*)d_in[0];
    const float* mem_r = (const float*)d_in[1];
    const float* mem_i = (const float*)d_in[2];
    const float* a     = (const float*)d_in[3];
    const float* bfrq  = (const float*)d_in[4];
    float* out = (float*)d_out;

    ffa_fused<<<BB * (MEMD / 2), 1024, 0, stream>>>(x, mem_r, mem_i, a, bfrq, out);
}